// Round 7
// baseline (287.151 us; speedup 1.0000x reference)
//
#include <hip/hip_runtime.h>
#include <stdint.h>

typedef short   shortx8 __attribute__((ext_vector_type(8)));
typedef float   f32x4   __attribute__((ext_vector_type(4)));
typedef float   f32x16  __attribute__((ext_vector_type(16)));

#define CPS 8

static __device__ __forceinline__ unsigned short f2bf(float f) {
  unsigned u = __float_as_uint(f);
  unsigned r = u + 0x7FFFu + ((u >> 16) & 1u);   // RTNE
  return (unsigned short)(r >> 16);
}

static __device__ __forceinline__ void gl2lds16(const void* gsrc, void* ldst) {
  __builtin_amdgcn_global_load_lds(
      (const __attribute__((address_space(1))) unsigned int*)gsrc,
      (__attribute__((address_space(3))) unsigned int*)ldst, 16, 0, 0);
}

// ---- K1: fused {X->bf16, aug = ||x||^2 - w} and {xt->bf16, q2}; 16B/lane loads ----
__global__ void k_prep(const float* __restrict__ X, const float* __restrict__ xt,
                       const float* __restrict__ w, unsigned short* __restrict__ xb,
                       unsigned short* __restrict__ qb, float* __restrict__ aug,
                       float* __restrict__ q2, int n, int npad, int xblocks, int B) {
  const int hw = threadIdx.x >> 5;           // half-wave 0..7
  const int hl = threadIdx.x & 31;
  const int col = hl * 4;
  if ((int)blockIdx.x < xblocks) {
    int r = blockIdx.x * 8 + hw;
    if (r < n) {
      f32x4 v = *(const f32x4*)(X + (size_t)r * 128 + col);
      ushort4 us = make_ushort4(f2bf(v[0]), f2bf(v[1]), f2bf(v[2]), f2bf(v[3]));
      *(ushort4*)(xb + (size_t)r * 128 + col) = us;
      float s = v[0] * v[0] + v[1] * v[1] + v[2] * v[2] + v[3] * v[3];
      for (int m = 16; m; m >>= 1) s += __shfl_xor(s, m);
      if (hl == 0) aug[r] = s - w[r];
    } else {
      *(ushort4*)(xb + (size_t)r * 128 + col) = make_ushort4(0, 0, 0, 0);
      if (hl == 0) aug[r] = 1e30f;
    }
  } else {
    int r = (blockIdx.x - xblocks) * 8 + hw;
    f32x4 v = *(const f32x4*)(xt + (size_t)r * 128 + col);
    ushort4 us = make_ushort4(f2bf(v[0]), f2bf(v[1]), f2bf(v[2]), f2bf(v[3]));
    *(ushort4*)(qb + (size_t)r * 128 + col) = us;
    float s = v[0] * v[0] + v[1] * v[1] + v[2] * v[2] + v[3] * v[3];
    for (int m = 16; m; m >>= 1) s += __shfl_xor(s, m);
    if (hl == 0) q2[r] = s;
  }
}

// ---- K2: bf16 MFMA 32x32x16 -> per-(query,chunk64) min of s' = aug - 2*dot ----
// 3-deep gl2lds pipeline, counted vmcnt + raw s_barrier (T3/T4), setprio (T5).
// C/D layout (m74/m101 verified): col=lane&31, row=(reg&3)+8*(reg>>2)+4*(lane>>5).
__global__ __launch_bounds__(256, 3) void k_gemm(const unsigned short* __restrict__ qb,
    const unsigned short* __restrict__ xb, const float* __restrict__ aug,
    float* __restrict__ cmin, int C) {
  __shared__ __align__(16) unsigned short tile[3][8192];   // 3 x 16KB; reused as out-bounce
  __shared__ __align__(16) float augs[CPS * 64];           // stripe aug values
  const int S = C / CPS;                     // 196 stripes
  const int b = blockIdx.x;
  const int xcd = b & 7;
  const int j = b >> 3;                      // 0..199
  const int sj = j % 25, xq = j / 25;        // xq 0..7
  const int qq = S >> 3, rr = S & 7;         // bijective split: 24, 4
  const int nst = (xcd < rr) ? (qq + 1) : qq;
  if (sj >= nst) return;
  const int ystripe = (xcd < rr) ? (xcd * (qq + 1) + sj)
                                 : (rr * (qq + 1) + (xcd - rr) * qq + sj);
  const int c0 = ystripe * CPS;

  const int t = threadIdx.x;
  const int lane = t & 63, wv = t >> 6;
  const int l31 = lane & 31, hi = lane >> 5;
  const int qbase = xq * 256 + wv * 64;

  // B operand: 64 queries x K=128 resident in registers.
  // 32x32x16 B layout: col=lane&31 (query), k = ks*16 + hi*8 + i.
  shortx8 qf[2][8];
#pragma unroll
  for (int qt = 0; qt < 2; ++qt)
#pragma unroll
    for (int ks = 0; ks < 8; ++ks)
      qf[qt][ks] = *(const shortx8*)(qb + (size_t)(qbase + qt * 32 + l31) * 128 + ks * 16 + hi * 8);

  // stripe aug -> LDS (2 floats/thread)
  {
    float2 a2 = *(const float2*)(aug + (size_t)c0 * 64 + t * 2);
    *(float2*)&augs[t * 2] = a2;
  }

  // pre-swizzled global source offsets (linear LDS dest, swizzled ds_read)
  int soff[4];
#pragma unroll
  for (int jj = 0; jj < 4; ++jj) {
    int o = wv * 4096 + jj * 1024 + lane * 16;
    int r = o >> 8;
    soff[jj] = (o & ~255) | ((o & 255) ^ ((r & 7) << 4));
  }

#define STAGE(buf, cc) do {                                                  \
    const char* _s = (const char*)xb + (size_t)(cc) * 16384;                 \
    _Pragma("unroll")                                                        \
    for (int _j = 0; _j < 4; ++_j)                                           \
      gl2lds16(_s + soff[_j], &tile[buf][wv * 2048 + _j * 512]);             \
  } while (0)

  float cm[2][CPS];    // [qt][chunk] per-lane (query = qbase+qt*32+l31; both halves)

  __syncthreads();                           // augs visible (also drains aug loads)
  STAGE(0, c0);
  STAGE(1, c0 + 1);

#pragma unroll
  for (int cc = 0; cc < CPS; ++cc) {
    const int cur = cc % 3;
    // wait oldest stage (chunk cc) landed; keep 1 stage in flight mid-loop (T4)
    if (cc < CPS - 1) asm volatile("s_waitcnt vmcnt(4)" ::: "memory");
    else              asm volatile("s_waitcnt vmcnt(0)" ::: "memory");
    __builtin_amdgcn_s_barrier();            // raw: no compiler vmcnt(0) drain
    __builtin_amdgcn_sched_barrier(0);
    if (cc + 2 < CPS) STAGE((cc + 2) % 3, c0 + cc + 2);

    f32x16 acc[2][2];
#pragma unroll
    for (int rg = 0; rg < 2; ++rg)
#pragma unroll
      for (int qt = 0; qt < 2; ++qt)
        acc[rg][qt] = (f32x16){0.f};

    __builtin_amdgcn_s_setprio(1);
#pragma unroll
    for (int rg = 0; rg < 2; ++rg) {
      const int r = rg * 32 + l31;           // A row = lane&31 within 32-group
      const int rsw = (r & 7) << 3;
      shortx8 af[8];
#pragma unroll
      for (int ks = 0; ks < 8; ++ks)
        af[ks] = *(const shortx8*)(&tile[cur][r * 128 + ((ks * 16 + hi * 8) ^ rsw)]);
#pragma unroll
      for (int qt = 0; qt < 2; ++qt)
#pragma unroll
        for (int ks = 0; ks < 8; ++ks)
          acc[rg][qt] = __builtin_amdgcn_mfma_f32_32x32x16_bf16(af[ks], qf[qt][ks], acc[rg][qt], 0, 0, 0);
    }
    __builtin_amdgcn_s_setprio(0);

    // aug per acc reg: row = rg*32 + (reg&3) + 8*(reg>>2) + 4*hi
    f32x4 agv[2][4];
#pragma unroll
    for (int rg = 0; rg < 2; ++rg)
#pragma unroll
      for (int r4 = 0; r4 < 4; ++r4)
        agv[rg][r4] = *(const f32x4*)&augs[cc * 64 + rg * 32 + 8 * r4 + 4 * hi];

#pragma unroll
    for (int qt = 0; qt < 2; ++qt) {
      float v = 1e38f;
#pragma unroll
      for (int rg = 0; rg < 2; ++rg)
#pragma unroll
        for (int r4 = 0; r4 < 4; ++r4)
#pragma unroll
          for (int e = 0; e < 4; ++e)
            v = fminf(v, fmaf(-2.f, acc[rg][qt][r4 * 4 + e], agv[rg][r4][e]));
      v = fminf(v, __shfl_xor(v, 32));       // combine hi halves (rows +4*hi)
      cm[qt][cc] = v;
    }
  }
#undef STAGE

  __syncthreads();                           // full drain before tile reuse as bounce
  // coalesced cmin write via LDS bounce (stride 12 floats: 16B-aligned reads)
  float* outf = (float*)tile;
  if (lane < 32) {
#pragma unroll
    for (int qt = 0; qt < 2; ++qt) {
      f32x4 v0 = {cm[qt][0], cm[qt][1], cm[qt][2], cm[qt][3]};
      f32x4 v1 = {cm[qt][4], cm[qt][5], cm[qt][6], cm[qt][7]};
      *(f32x4*)&outf[(wv * 64 + qt * 32 + l31) * 12]     = v0;
      *(f32x4*)&outf[(wv * 64 + qt * 32 + l31) * 12 + 4] = v1;
    }
  }
  __syncthreads();
#pragma unroll
  for (int p = 0; p < 2; ++p) {
    int flat = p * 1024 + t * 4;
    int ql = flat >> 3, cix = flat & 7;      // cix in {0,4}
    f32x4 v = *(const f32x4*)&outf[ql * 12 + cix];
    *(f32x4*)&cmin[(size_t)(xq * 256 + ql) * C + c0 + cix] = v;
  }
}

// ---- K3: tau = (k-th smallest chunk-min)+1.5, fused per-chunk list append ----
__global__ void k_tau(const float* __restrict__ cmin, float* __restrict__ tau,
                      const int* __restrict__ kptr, int* __restrict__ ccnt,
                      int* __restrict__ clist, int C, int B) {
  __shared__ float arr[1600];
  __shared__ float red[4];
  __shared__ int   redi[4];
  __shared__ float bval;
  __shared__ int   bidx;
  const int q = blockIdx.x, t = threadIdx.x;
  const int lane = t & 63, wv = t >> 6;
  const float* row = cmin + (size_t)q * C;
  float lmd = 1e38f; int lmi = -1;
  for (int i = t; i < C; i += 256) {
    float v = row[i]; arr[i] = v;
    if (v < lmd) { lmd = v; lmi = i; }
  }
  __syncthreads();
  int k = *kptr; if (k < 1) k = 1; if (k > 32) k = 32;
  float tv = 1e38f;
  for (int r = 0; r < k; ++r) {
    float md = lmd; int mi = lmi;
    for (int msk = 32; msk; msk >>= 1) {
      float od = __shfl_xor(md, msk); int oi = __shfl_xor(mi, msk);
      if (od < md) { md = od; mi = oi; }
    }
    if (lane == 0) { red[wv] = md; redi[wv] = mi; }
    __syncthreads();
    if (t == 0) {
      float bm = red[0]; int bi = redi[0];
      for (int u = 1; u < 4; ++u) if (red[u] < bm) { bm = red[u]; bi = redi[u]; }
      bval = bm; bidx = bi;
    }
    __syncthreads();
    tv = bval;
    const int sel = bidx;
    if (r + 1 < k && sel >= 0 && (sel & 255) == t) {
      arr[sel] = 1e38f;
      lmd = 1e38f; lmi = -1;
      for (int i = t; i < C; i += 256) {
        float v = arr[i];
        if (v < lmd) { lmd = v; lmi = i; }
      }
    }
    __syncthreads();
  }
  const float tq = tv + 1.5f;
  if (t == 0) tau[q] = tq;
  for (int i = t; i < C; i += 256)
    if (row[i] <= tq) {
      int pos = atomicAdd(&ccnt[i], 1);
      clist[(size_t)i * B + pos] = q;
    }
}

// ---- K4: exact fp32 recompute; per-wave independent rounds of 4 queries ----
__global__ __launch_bounds__(256) void k_exact(const float* __restrict__ X, const float* __restrict__ xt,
    const float* __restrict__ aug, const float* __restrict__ q2, const float* __restrict__ tau,
    const int* __restrict__ ccnt, const int* __restrict__ clist,
    int* __restrict__ qcnt, float2* __restrict__ cand, int n, int B) {
  const int c = blockIdx.x;
  const int nq = ccnt[c];
  if (nq == 0) return;
  __shared__ float xs[64 * 128];     // swizzled quads
  __shared__ float qs[4 * 512];      // 4 waves x 4 queries x 128
  const int t = threadIdx.x, lane = t & 63, wv = t >> 6;
#pragma unroll
  for (int p = 0; p < 8; ++p) {
    int flat = p * 1024 + t * 4;
    int r = flat >> 7, col = flat & 127;
    long g = (long)c * 64 + r;
    f32x4 v = (f32x4){0.f, 0.f, 0.f, 0.f};
    if (g < n) v = *(const f32x4*)(X + g * 128 + col);
    *(f32x4*)&xs[r * 128 + ((((col >> 2) ^ (r & 31))) << 2)] = v;
  }
  const int gcol = c * 64 + lane;
  const float augv = aug[gcol];
  __syncthreads();

  float* qsw = qs + wv * 512;
  const int sw = lane & 31;
  const int su = (lane >> 4) & 3;           // staging: which query this lane loads
  const int scol = (lane & 15) * 8;
  for (int i0 = wv * 4; i0 < nq; i0 += 16) {
    const size_t cb = (size_t)c * B;
    int qn0 = __builtin_amdgcn_readfirstlane(clist[cb + min(i0 + 0, nq - 1)]);
    int qn1 = __builtin_amdgcn_readfirstlane(clist[cb + min(i0 + 1, nq - 1)]);
    int qn2 = __builtin_amdgcn_readfirstlane(clist[cb + min(i0 + 2, nq - 1)]);
    int qn3 = __builtin_amdgcn_readfirstlane(clist[cb + min(i0 + 3, nq - 1)]);
    {  // stage this wave's 4 queries (8 floats/lane)
      int qnu = (su == 0) ? qn0 : (su == 1) ? qn1 : (su == 2) ? qn2 : qn3;
      const float* Q = xt + (size_t)qnu * 128 + scol;
      *(f32x4*)&qsw[su * 128 + scol]     = *(const f32x4*)(Q);
      *(f32x4*)&qsw[su * 128 + scol + 4] = *(const f32x4*)(Q + 4);
    }
    float t0 = tau[qn0], t1 = tau[qn1], t2 = tau[qn2], t3 = tau[qn3];
    float g0 = q2[qn0], g1 = q2[qn1], g2 = q2[qn2], g3 = q2[qn3];
    float a0 = 0.f, a1 = 0.f, a2 = 0.f, a3 = 0.f;
#pragma unroll 4
    for (int jj = 0; jj < 32; ++jj) {
      f32x4 xv = *(const f32x4*)&xs[lane * 128 + ((jj ^ sw) << 2)];
      f32x4 v0 = *(const f32x4*)&qsw[0 * 128 + jj * 4];
      f32x4 v1 = *(const f32x4*)&qsw[1 * 128 + jj * 4];
      f32x4 v2 = *(const f32x4*)&qsw[2 * 128 + jj * 4];
      f32x4 v3 = *(const f32x4*)&qsw[3 * 128 + jj * 4];
#pragma unroll
      for (int e = 0; e < 4; ++e) {
        a0 = fmaf(xv[e], v0[e], a0);
        a1 = fmaf(xv[e], v1[e], a1);
        a2 = fmaf(xv[e], v2[e], a2);
        a3 = fmaf(xv[e], v3[e], a3);
      }
    }
#pragma unroll
    for (int u = 0; u < 4; ++u) {
      const float accv = (u == 0) ? a0 : (u == 1) ? a1 : (u == 2) ? a2 : a3;
      const int qnu   = (u == 0) ? qn0 : (u == 1) ? qn1 : (u == 2) ? qn2 : qn3;
      const float tuu = (u == 0) ? t0 : (u == 1) ? t1 : (u == 2) ? t2 : t3;
      const float g2u = (u == 0) ? g0 : (u == 1) ? g1 : (u == 2) ? g2 : g3;
      const float s = fmaf(-2.f, accv, augv);
      if ((i0 + u) < nq && gcol < n && s <= tuu) {
        int pos = atomicAdd(&qcnt[qnu], 1);
        if (pos < 256) {
          float d2v = fmaf(-2.f, accv, g2u) + augv;
          cand[(size_t)qnu * 256 + pos] = make_float2(d2v, __int_as_float(gcol));
        }
      }
    }
  }
}

// ---- K5: exact top-k (ascending (d2',idx)) + argmax f; f = w - sqrt(relu(d2'+w)) ----
__global__ void k_final(const float* __restrict__ w,
    const float2* __restrict__ cand, const int* __restrict__ qcnt, const int* __restrict__ kptr,
    float* __restrict__ dout, int B, int n) {
  const int q = blockIdx.x, lane = threadIdx.x;
  int k = *kptr; if (k < 1) k = 1; if (k > 64) k = 64;
  const int cnt = min(qcnt[q], 256);
  float d0 = 1e38f, d1 = 1e38f, d2v = 1e38f, d3 = 1e38f;
  int i0 = 0x7fffffff, i1 = 0x7fffffff, i2 = 0x7fffffff, i3 = 0x7fffffff;
  {
    int s;
    s = lane;       if (s < cnt) { float2 cc = cand[(size_t)q * 256 + s]; d0 = cc.x; i0 = __float_as_int(cc.y); }
    s = lane + 64;  if (s < cnt) { float2 cc = cand[(size_t)q * 256 + s]; d1 = cc.x; i1 = __float_as_int(cc.y); }
    s = lane + 128; if (s < cnt) { float2 cc = cand[(size_t)q * 256 + s]; d2v = cc.x; i2 = __float_as_int(cc.y); }
    s = lane + 192; if (s < cnt) { float2 cc = cand[(size_t)q * 256 + s]; d3 = cc.x; i3 = __float_as_int(cc.y); }
  }
  float bestf = -1e38f; int besti = 0;
  for (int r = 0; r < k; ++r) {
    float md = d0; int mi = i0; int mj = 0;
    if (d1 < md || (d1 == md && i1 < mi)) { md = d1; mi = i1; mj = 1; }
    if (d2v < md || (d2v == md && i2 < mi)) { md = d2v; mi = i2; mj = 2; }
    if (d3 < md || (d3 == md && i3 < mi)) { md = d3; mi = i3; mj = 3; }
    int ml = lane;
    for (int msk = 32; msk; msk >>= 1) {
      float od = __shfl_xor(md, msk); int oi = __shfl_xor(mi, msk);
      int ol = __shfl_xor(ml, msk);   int oj = __shfl_xor(mj, msk);
      if (od < md || (od == md && oi < mi)) { md = od; mi = oi; ml = ol; mj = oj; }
    }
    if (lane == ml) {
      if (mj == 0)      { d0 = 1e38f;  i0 = 0x7fffffff; }
      else if (mj == 1) { d1 = 1e38f;  i1 = 0x7fffffff; }
      else if (mj == 2) { d2v = 1e38f; i2 = 0x7fffffff; }
      else              { d3 = 1e38f;  i3 = 0x7fffffff; }
    }
    if (mi >= 0 && mi < n) {
      float wi = w[mi];
      float da = sqrtf(fmaxf(md + wi, 0.f));
      float f = wi - da;
      if (f > bestf) { bestf = f; besti = mi; }
    }
  }
  if (lane == 0) { dout[q] = bestf; dout[B + q] = (float)besti; }
}

extern "C" void kernel_launch(void* const* d_in, const int* in_sizes, int n_in,
                              void* d_out, int out_size, void* d_ws, size_t ws_size,
                              hipStream_t stream) {
  const float* xt = (const float*)d_in[0];
  const float* X  = (const float*)d_in[1];
  const float* w  = (const float*)d_in[2];
  const int* kptr = (const int*)d_in[3];
  const int B = in_sizes[0] / 128;            // 2048
  const int n = in_sizes[2];                  // 100000
  const int C = ((n + 63) / 64 + CPS - 1) / CPS * CPS;  // 1568 (stripe multiple)
  const int npad = C * 64;                    // 100352

  char* ws = (char*)d_ws;
  const size_t o_ccnt = 0;                                   // C ints (<= 8192 B)
  const size_t o_qcnt = 8192;                                // B ints
  const size_t o_q2   = 16384;
  const size_t o_tau  = o_q2 + (size_t)B * 4;
  const size_t o_aug  = o_tau + (size_t)B * 4;
  const size_t o_cmin = (o_aug + (size_t)npad * 4 + 255) & ~(size_t)255;
  const size_t o_clist= (o_cmin + (size_t)B * C * 4 + 255) & ~(size_t)255;
  const size_t o_cand = (o_clist + (size_t)C * B * 4 + 255) & ~(size_t)255;
  const size_t o_qb   = (o_cand + (size_t)B * 256 * 8 + 255) & ~(size_t)255;
  const size_t o_xb   = (o_qb + (size_t)B * 128 * 2 + 255) & ~(size_t)255;

  int* ccnt  = (int*)(ws + o_ccnt);
  int* qcnt  = (int*)(ws + o_qcnt);
  float* q2  = (float*)(ws + o_q2);
  float* tau = (float*)(ws + o_tau);
  float* aug = (float*)(ws + o_aug);
  float* cmin = (float*)(ws + o_cmin);
  int* clist = (int*)(ws + o_clist);
  float2* cand = (float2*)(ws + o_cand);
  unsigned short* qb = (unsigned short*)(ws + o_qb);
  unsigned short* xb = (unsigned short*)(ws + o_xb);

  hipMemsetAsync(d_ws, 0, 16384, stream);     // ccnt + qcnt

  const int xblocks = npad / 8;               // 12544
  k_prep<<<xblocks + B / 8, 256, 0, stream>>>(X, xt, w, xb, qb, aug, q2, n, npad, xblocks, B);

  k_gemm<<<1600, 256, 0, stream>>>(qb, xb, aug, cmin, C);   // 8 xcd x 25 sj x 8 xq

  k_tau<<<B, 256, 0, stream>>>(cmin, tau, kptr, ccnt, clist, C, B);
  k_exact<<<C, 256, 0, stream>>>(X, xt, aug, q2, tau, ccnt, clist, qcnt, cand, n, B);
  k_final<<<B, 64, 0, stream>>>(w, cand, qcnt, kptr, (float*)d_out, B, n);
}

// Round 8
// 231.998 us; speedup vs baseline: 1.2377x; 1.2377x over previous
//
#include <hip/hip_runtime.h>
#include <stdint.h>

typedef short   shortx8 __attribute__((ext_vector_type(8)));
typedef float   f32x4   __attribute__((ext_vector_type(4)));

#define CPS 8

static __device__ __forceinline__ unsigned short f2bf(float f) {
  unsigned u = __float_as_uint(f);
  unsigned r = u + 0x7FFFu + ((u >> 16) & 1u);   // RTNE
  return (unsigned short)(r >> 16);
}

static __device__ __forceinline__ void gl2lds16(const void* gsrc, void* ldst) {
  __builtin_amdgcn_global_load_lds(
      (const __attribute__((address_space(1))) unsigned int*)gsrc,
      (__attribute__((address_space(3))) unsigned int*)ldst, 16, 0, 0);
}

// ---- K1: fused {X->bf16, aug = ||x||^2 - w} and {xt->bf16, q2}; 16B/lane loads.
//      Last block zeroes ccnt/qcnt (replaces the hipMemsetAsync launch). ----
__global__ void k_prep(const float* __restrict__ X, const float* __restrict__ xt,
                       const float* __restrict__ w, unsigned short* __restrict__ xb,
                       unsigned short* __restrict__ qb, float* __restrict__ aug,
                       float* __restrict__ q2, int* __restrict__ wszero,
                       int n, int npad, int xblocks, int B) {
  const int hw = threadIdx.x >> 5;           // half-wave 0..7
  const int hl = threadIdx.x & 31;
  const int col = hl * 4;
  if ((int)blockIdx.x < xblocks) {
    int r = blockIdx.x * 8 + hw;
    if (r < n) {
      f32x4 v = *(const f32x4*)(X + (size_t)r * 128 + col);
      ushort4 us = make_ushort4(f2bf(v[0]), f2bf(v[1]), f2bf(v[2]), f2bf(v[3]));
      *(ushort4*)(xb + (size_t)r * 128 + col) = us;
      float s = v[0] * v[0] + v[1] * v[1] + v[2] * v[2] + v[3] * v[3];
      for (int m = 16; m; m >>= 1) s += __shfl_xor(s, m);
      if (hl == 0) aug[r] = s - w[r];
    } else {
      *(ushort4*)(xb + (size_t)r * 128 + col) = make_ushort4(0, 0, 0, 0);
      if (hl == 0) aug[r] = 1e30f;
    }
  } else if ((int)blockIdx.x < xblocks + B / 8) {
    int r = (blockIdx.x - xblocks) * 8 + hw;
    f32x4 v = *(const f32x4*)(xt + (size_t)r * 128 + col);
    ushort4 us = make_ushort4(f2bf(v[0]), f2bf(v[1]), f2bf(v[2]), f2bf(v[3]));
    *(ushort4*)(qb + (size_t)r * 128 + col) = us;
    float s = v[0] * v[0] + v[1] * v[1] + v[2] * v[2] + v[3] * v[3];
    for (int m = 16; m; m >>= 1) s += __shfl_xor(s, m);
    if (hl == 0) q2[r] = s;
  } else {
    // zero ccnt (ws[0..8191]) + qcnt (ws[8192..16383]) = 4096 ints
    int4* p = (int4*)wszero;
#pragma unroll
    for (int i = 0; i < 4; ++i)
      p[i * 256 + threadIdx.x] = make_int4(0, 0, 0, 0);
  }
}

// ---- K2: bf16 MFMA 16x16x32 -> per-(query,chunk64) min of s' = aug - 2*dot ----
// T3/T4: 3-deep gl2lds pipeline, counted vmcnt (never 0 mid-loop) + raw
// s_barrier; aug in LDS; T5 setprio around MFMA. (R6-measured: 57.5us, 36% Mfma)
__global__ __launch_bounds__(256, 3) void k_gemm(const unsigned short* __restrict__ qb,
    const unsigned short* __restrict__ xb, const float* __restrict__ aug,
    float* __restrict__ cmin, int C) {
  __shared__ __align__(16) unsigned short tile[3][8192];   // 3 x 16KB; reused as out-bounce
  __shared__ __align__(16) float augs[CPS * 64];           // stripe aug values
  const int S = C / CPS;                     // 196 stripes
  const int b = blockIdx.x;
  const int xcd = b & 7;
  const int j = b >> 3;                      // 0..199
  const int sj = j % 25, xq = j / 25;        // xq 0..7
  const int qq = S >> 3, rr = S & 7;         // bijective split: 24, 4
  const int nst = (xcd < rr) ? (qq + 1) : qq;
  if (sj >= nst) return;
  const int ystripe = (xcd < rr) ? (xcd * (qq + 1) + sj)
                                 : (rr * (qq + 1) + (xcd - rr) * qq + sj);
  const int c0 = ystripe * CPS;

  const int t = threadIdx.x;
  const int lane = t & 63, wv = t >> 6;
  const int li = lane & 15, lg = lane >> 4;
  const int qbase = xq * 256 + wv * 64;

  // B operand: 64 queries x K=128 resident in registers
  shortx8 qf[4][4];
#pragma unroll
  for (int qt = 0; qt < 4; ++qt)
#pragma unroll
    for (int ks = 0; ks < 4; ++ks)
      qf[qt][ks] = *(const shortx8*)(qb + (size_t)(qbase + qt * 16 + li) * 128 + ks * 32 + lg * 8);

  // stripe aug -> LDS (2 floats/thread)
  {
    float2 a2 = *(const float2*)(aug + (size_t)c0 * 64 + t * 2);
    *(float2*)&augs[t * 2] = a2;
  }

  // pre-swizzled global source offsets (linear LDS dest, swizzled ds_read)
  int soff[4];
#pragma unroll
  for (int jj = 0; jj < 4; ++jj) {
    int o = wv * 4096 + jj * 1024 + lane * 16;
    int r = o >> 8;
    soff[jj] = (o & ~255) | ((o & 255) ^ ((r & 7) << 4));
  }

#define STAGE(buf, cc) do {                                                  \
    const char* _s = (const char*)xb + (size_t)(cc) * 16384;                 \
    _Pragma("unroll")                                                        \
    for (int _j = 0; _j < 4; ++_j)                                           \
      gl2lds16(_s + soff[_j], &tile[buf][wv * 2048 + _j * 512]);             \
  } while (0)

  float cm[4][2];      // [qt][chunk>>2], owner lane: lg == chunk&3
#pragma unroll
  for (int qt = 0; qt < 4; ++qt)
#pragma unroll
    for (int jj = 0; jj < 2; ++jj) cm[qt][jj] = 1e38f;

  __syncthreads();                           // augs visible (also drains aug loads)
  STAGE(0, c0);
  STAGE(1, c0 + 1);

#pragma unroll
  for (int cc = 0; cc < CPS; ++cc) {
    const int cur = cc % 3;
    // wait oldest stage (chunk cc) landed; keep 1 stage in flight mid-loop (T4)
    if (cc < CPS - 1) asm volatile("s_waitcnt vmcnt(4)" ::: "memory");
    else              asm volatile("s_waitcnt vmcnt(0)" ::: "memory");
    __builtin_amdgcn_s_barrier();            // raw: no compiler vmcnt(0) drain
    __builtin_amdgcn_sched_barrier(0);
    if (cc + 2 < CPS) STAGE((cc + 2) % 3, c0 + cc + 2);

    f32x4 acc[4][4];
#pragma unroll
    for (int rg = 0; rg < 4; ++rg)
#pragma unroll
      for (int qt = 0; qt < 4; ++qt)
        acc[rg][qt] = (f32x4){0.f, 0.f, 0.f, 0.f};

    __builtin_amdgcn_s_setprio(1);
#pragma unroll
    for (int rg = 0; rg < 4; ++rg) {
      const int r = rg * 16 + li;
      const int rsw = (r & 7) << 3;
      shortx8 af[4];
#pragma unroll
      for (int ks = 0; ks < 4; ++ks)
        af[ks] = *(const shortx8*)(&tile[cur][r * 128 + ((ks * 32 + lg * 8) ^ rsw)]);
#pragma unroll
      for (int qt = 0; qt < 4; ++qt)
#pragma unroll
        for (int ks = 0; ks < 4; ++ks)
          acc[rg][qt] = __builtin_amdgcn_mfma_f32_16x16x32_bf16(af[ks], qf[qt][ks], acc[rg][qt], 0, 0, 0);
    }
    __builtin_amdgcn_s_setprio(0);

    float m[4];
#pragma unroll
    for (int qt = 0; qt < 4; ++qt) {
      float v = 1e38f;
#pragma unroll
      for (int rg = 0; rg < 4; ++rg) {
        f32x4 avv = *(const f32x4*)&augs[cc * 64 + rg * 16 + lg * 4];
#pragma unroll
        for (int p = 0; p < 4; ++p)
          v = fminf(v, fmaf(-2.f, acc[rg][qt][p], avv[p]));
      }
      v = fminf(v, __shfl_xor(v, 16));
      v = fminf(v, __shfl_xor(v, 32));
      m[qt] = v;
    }
#pragma unroll
    for (int qt = 0; qt < 4; ++qt)
      cm[qt][cc >> 2] = (lg == (cc & 3)) ? m[qt] : cm[qt][cc >> 2];
  }
#undef STAGE

  __syncthreads();                           // full drain before tile reuse as bounce
  // coalesced cmin write via LDS bounce (stride 12 floats: 16B-aligned reads)
  float* outf = (float*)tile;
#pragma unroll
  for (int qt = 0; qt < 4; ++qt)
#pragma unroll
    for (int jj = 0; jj < 2; ++jj)
      outf[(wv * 64 + qt * 16 + li) * 12 + jj * 4 + lg] = cm[qt][jj];
  __syncthreads();
#pragma unroll
  for (int p = 0; p < 2; ++p) {
    int flat = p * 1024 + t * 4;
    int ql = flat >> 3, cix = flat & 7;      // cix in {0,4}
    f32x4 v = *(const f32x4*)&outf[ql * 12 + cix];
    *(f32x4*)&cmin[(size_t)(xq * 256 + ql) * C + c0 + cix] = v;
  }
}

// ---- K3: tau = (k-th smallest chunk-min)+1.5, fused per-chunk list append ----
// 256 threads stage row -> LDS; wave 0 runs all k selection rounds barrier-free
// (shfl butterfly + owner-slice rescan); one barrier; all threads append.
__global__ void k_tau(const float* __restrict__ cmin, float* __restrict__ tau,
                      const int* __restrict__ kptr, int* __restrict__ ccnt,
                      int* __restrict__ clist, int C, int B) {
  __shared__ float arr[1600];
  __shared__ float tau_s;
  const int q = blockIdx.x, t = threadIdx.x;
  const float* row = cmin + (size_t)q * C;
  for (int i = t * 4; i < C; i += 1024)
    *(f32x4*)&arr[i] = *(const f32x4*)(row + i);
  __syncthreads();
  if (t < 64) {
    int k = *kptr; if (k < 1) k = 1; if (k > 32) k = 32;
    float lmd = 1e38f; int lmi = -1;
    for (int i = t; i < C; i += 64) {
      float v = arr[i];
      if (v < lmd) { lmd = v; lmi = i; }
    }
    float tv = 1e38f;
    for (int r = 0; r < k; ++r) {
      float md = lmd; int mi = lmi; int ml = t;
      for (int msk = 32; msk; msk >>= 1) {
        float od = __shfl_xor(md, msk); int oi = __shfl_xor(mi, msk); int ol = __shfl_xor(ml, msk);
        if (od < md) { md = od; mi = oi; ml = ol; }
      }
      tv = md;
      if (r + 1 < k && t == ml) {            // owner removes + rescans its slice
        arr[mi] = 1e38f;
        lmd = 1e38f; lmi = -1;
        for (int i = t; i < C; i += 64) {
          float v = arr[i];
          if (v < lmd) { lmd = v; lmi = i; }
        }
      }
    }
    if (t == 0) { tau_s = tv + 1.5f; tau[q] = tv + 1.5f; }
  }
  __syncthreads();
  const float tq = tau_s;
  for (int i = t; i < C; i += 256)           // append from global row (arr has
    if (row[i] <= tq) {                      // the removed minima poisoned!)
      int pos = atomicAdd(&ccnt[i], 1);
      clist[(size_t)i * B + pos] = q;
    }
}

// ---- K4: exact fp32 recompute; per-wave independent rounds of 4 queries ----
__global__ __launch_bounds__(256) void k_exact(const float* __restrict__ X, const float* __restrict__ xt,
    const float* __restrict__ aug, const float* __restrict__ q2, const float* __restrict__ tau,
    const int* __restrict__ ccnt, const int* __restrict__ clist,
    int* __restrict__ qcnt, float2* __restrict__ cand, int n, int B) {
  const int c = blockIdx.x;
  const int nq = ccnt[c];
  if (nq == 0) return;
  __shared__ float xs[64 * 128];     // swizzled quads
  __shared__ float qs[4 * 512];      // 4 waves x 4 queries x 128
  const int t = threadIdx.x, lane = t & 63, wv = t >> 6;
#pragma unroll
  for (int p = 0; p < 8; ++p) {
    int flat = p * 1024 + t * 4;
    int r = flat >> 7, col = flat & 127;
    long g = (long)c * 64 + r;
    f32x4 v = (f32x4){0.f, 0.f, 0.f, 0.f};
    if (g < n) v = *(const f32x4*)(X + g * 128 + col);
    *(f32x4*)&xs[r * 128 + ((((col >> 2) ^ (r & 31))) << 2)] = v;
  }
  const int gcol = c * 64 + lane;
  const float augv = aug[gcol];
  __syncthreads();

  float* qsw = qs + wv * 512;
  const int sw = lane & 31;
  const int su = (lane >> 4) & 3;           // staging: which query this lane loads
  const int scol = (lane & 15) * 8;
  for (int i0 = wv * 4; i0 < nq; i0 += 16) {
    const size_t cb = (size_t)c * B;
    int qn0 = __builtin_amdgcn_readfirstlane(clist[cb + min(i0 + 0, nq - 1)]);
    int qn1 = __builtin_amdgcn_readfirstlane(clist[cb + min(i0 + 1, nq - 1)]);
    int qn2 = __builtin_amdgcn_readfirstlane(clist[cb + min(i0 + 2, nq - 1)]);
    int qn3 = __builtin_amdgcn_readfirstlane(clist[cb + min(i0 + 3, nq - 1)]);
    {  // stage this wave's 4 queries (8 floats/lane)
      int qnu = (su == 0) ? qn0 : (su == 1) ? qn1 : (su == 2) ? qn2 : qn3;
      const float* Q = xt + (size_t)qnu * 128 + scol;
      *(f32x4*)&qsw[su * 128 + scol]     = *(const f32x4*)(Q);
      *(f32x4*)&qsw[su * 128 + scol + 4] = *(const f32x4*)(Q + 4);
    }
    float t0 = tau[qn0], t1 = tau[qn1], t2 = tau[qn2], t3 = tau[qn3];
    float g0 = q2[qn0], g1 = q2[qn1], g2 = q2[qn2], g3 = q2[qn3];
    float a0 = 0.f, a1 = 0.f, a2 = 0.f, a3 = 0.f;
#pragma unroll 4
    for (int jj = 0; jj < 32; ++jj) {
      f32x4 xv = *(const f32x4*)&xs[lane * 128 + ((jj ^ sw) << 2)];
      f32x4 v0 = *(const f32x4*)&qsw[0 * 128 + jj * 4];
      f32x4 v1 = *(const f32x4*)&qsw[1 * 128 + jj * 4];
      f32x4 v2 = *(const f32x4*)&qsw[2 * 128 + jj * 4];
      f32x4 v3 = *(const f32x4*)&qsw[3 * 128 + jj * 4];
#pragma unroll
      for (int e = 0; e < 4; ++e) {
        a0 = fmaf(xv[e], v0[e], a0);
        a1 = fmaf(xv[e], v1[e], a1);
        a2 = fmaf(xv[e], v2[e], a2);
        a3 = fmaf(xv[e], v3[e], a3);
      }
    }
#pragma unroll
    for (int u = 0; u < 4; ++u) {
      const float accv = (u == 0) ? a0 : (u == 1) ? a1 : (u == 2) ? a2 : a3;
      const int qnu   = (u == 0) ? qn0 : (u == 1) ? qn1 : (u == 2) ? qn2 : qn3;
      const float tuu = (u == 0) ? t0 : (u == 1) ? t1 : (u == 2) ? t2 : t3;
      const float g2u = (u == 0) ? g0 : (u == 1) ? g1 : (u == 2) ? g2 : g3;
      const float s = fmaf(-2.f, accv, augv);
      if ((i0 + u) < nq && gcol < n && s <= tuu) {
        int pos = atomicAdd(&qcnt[qnu], 1);
        if (pos < 256) {
          float d2v = fmaf(-2.f, accv, g2u) + augv;
          cand[(size_t)qnu * 256 + pos] = make_float2(d2v, __int_as_float(gcol));
        }
      }
    }
  }
}

// ---- K5: exact top-k (ascending (d2',idx)) + argmax f; f = w - sqrt(relu(d2'+w)) ----
__global__ void k_final(const float* __restrict__ w,
    const float2* __restrict__ cand, const int* __restrict__ qcnt, const int* __restrict__ kptr,
    float* __restrict__ dout, int B, int n) {
  const int q = blockIdx.x, lane = threadIdx.x;
  int k = *kptr; if (k < 1) k = 1; if (k > 64) k = 64;
  const int cnt = min(qcnt[q], 256);
  float d0 = 1e38f, d1 = 1e38f, d2v = 1e38f, d3 = 1e38f;
  int i0 = 0x7fffffff, i1 = 0x7fffffff, i2 = 0x7fffffff, i3 = 0x7fffffff;
  {
    int s;
    s = lane;       if (s < cnt) { float2 cc = cand[(size_t)q * 256 + s]; d0 = cc.x; i0 = __float_as_int(cc.y); }
    s = lane + 64;  if (s < cnt) { float2 cc = cand[(size_t)q * 256 + s]; d1 = cc.x; i1 = __float_as_int(cc.y); }
    s = lane + 128; if (s < cnt) { float2 cc = cand[(size_t)q * 256 + s]; d2v = cc.x; i2 = __float_as_int(cc.y); }
    s = lane + 192; if (s < cnt) { float2 cc = cand[(size_t)q * 256 + s]; d3 = cc.x; i3 = __float_as_int(cc.y); }
  }
  float bestf = -1e38f; int besti = 0;
  for (int r = 0; r < k; ++r) {
    float md = d0; int mi = i0; int mj = 0;
    if (d1 < md || (d1 == md && i1 < mi)) { md = d1; mi = i1; mj = 1; }
    if (d2v < md || (d2v == md && i2 < mi)) { md = d2v; mi = i2; mj = 2; }
    if (d3 < md || (d3 == md && i3 < mi)) { md = d3; mi = i3; mj = 3; }
    int ml = lane;
    for (int msk = 32; msk; msk >>= 1) {
      float od = __shfl_xor(md, msk); int oi = __shfl_xor(mi, msk);
      int ol = __shfl_xor(ml, msk);   int oj = __shfl_xor(mj, msk);
      if (od < md || (od == md && oi < mi)) { md = od; mi = oi; ml = ol; mj = oj; }
    }
    if (lane == ml) {
      if (mj == 0)      { d0 = 1e38f;  i0 = 0x7fffffff; }
      else if (mj == 1) { d1 = 1e38f;  i1 = 0x7fffffff; }
      else if (mj == 2) { d2v = 1e38f; i2 = 0x7fffffff; }
      else              { d3 = 1e38f;  i3 = 0x7fffffff; }
    }
    if (mi >= 0 && mi < n) {
      float wi = w[mi];
      float da = sqrtf(fmaxf(md + wi, 0.f));
      float f = wi - da;
      if (f > bestf) { bestf = f; besti = mi; }
    }
  }
  if (lane == 0) { dout[q] = bestf; dout[B + q] = (float)besti; }
}

extern "C" void kernel_launch(void* const* d_in, const int* in_sizes, int n_in,
                              void* d_out, int out_size, void* d_ws, size_t ws_size,
                              hipStream_t stream) {
  const float* xt = (const float*)d_in[0];
  const float* X  = (const float*)d_in[1];
  const float* w  = (const float*)d_in[2];
  const int* kptr = (const int*)d_in[3];
  const int B = in_sizes[0] / 128;            // 2048
  const int n = in_sizes[2];                  // 100000
  const int C = ((n + 63) / 64 + CPS - 1) / CPS * CPS;  // 1568 (stripe multiple)
  const int npad = C * 64;                    // 100352

  char* ws = (char*)d_ws;
  const size_t o_ccnt = 0;                                   // C ints (<= 8192 B)
  const size_t o_qcnt = 8192;                                // B ints
  const size_t o_q2   = 16384;
  const size_t o_tau  = o_q2 + (size_t)B * 4;
  const size_t o_aug  = o_tau + (size_t)B * 4;
  const size_t o_cmin = (o_aug + (size_t)npad * 4 + 255) & ~(size_t)255;
  const size_t o_clist= (o_cmin + (size_t)B * C * 4 + 255) & ~(size_t)255;
  const size_t o_cand = (o_clist + (size_t)C * B * 4 + 255) & ~(size_t)255;
  const size_t o_qb   = (o_cand + (size_t)B * 256 * 8 + 255) & ~(size_t)255;
  const size_t o_xb   = (o_qb + (size_t)B * 128 * 2 + 255) & ~(size_t)255;

  int* ccnt  = (int*)(ws + o_ccnt);
  int* qcnt  = (int*)(ws + o_qcnt);
  float* q2  = (float*)(ws + o_q2);
  float* tau = (float*)(ws + o_tau);
  float* aug = (float*)(ws + o_aug);
  float* cmin = (float*)(ws + o_cmin);
  int* clist = (int*)(ws + o_clist);
  float2* cand = (float2*)(ws + o_cand);
  unsigned short* qb = (unsigned short*)(ws + o_qb);
  unsigned short* xb = (unsigned short*)(ws + o_xb);

  const int xblocks = npad / 8;               // 12544
  k_prep<<<xblocks + B / 8 + 1, 256, 0, stream>>>(X, xt, w, xb, qb, aug, q2,
                                                  (int*)ws, n, npad, xblocks, B);

  k_gemm<<<1600, 256, 0, stream>>>(qb, xb, aug, cmin, C);   // 8 xcd x 25 sj x 8 xq

  k_tau<<<B, 256, 0, stream>>>(cmin, tau, kptr, ccnt, clist, C, B);
  k_exact<<<C, 256, 0, stream>>>(X, xt, aug, q2, tau, ccnt, clist, qcnt, cand, n, B);
  k_final<<<B, 64, 0, stream>>>(w, cand, qcnt, kptr, (float*)d_out, B, n);
}